// Round 1
// baseline (1349.977 us; speedup 1.0000x reference)
//
#include <hip/hip_runtime.h>

#define TILE 128
#define D 64

// ---------------------------------------------------------------------------
// Row-norm precompute. Padded entries (row >= n) get 1e30 so that
// sq = na + nb - 2*dot ~ 1e30 -> exp2(-0.72*1e30) == 0 (free boundary mask).
// ---------------------------------------------------------------------------
__global__ void norms_kernel(const float* __restrict__ X, const float* __restrict__ Y,
                             float* __restrict__ nx, float* __restrict__ ny,
                             int nX, int nY, int padN) {
    int i = blockIdx.x * blockDim.x + threadIdx.x;
    if (i < padN) {
        float s = 1e30f;
        if (i < nX) {
            s = 0.f;
            const float4* p = (const float4*)(X + (size_t)i * D);
#pragma unroll
            for (int c = 0; c < D / 4; ++c) {
                float4 v = p[c];
                s += v.x * v.x + v.y * v.y + v.z * v.z + v.w * v.w;
            }
        }
        nx[i] = s;
    } else if (i < 2 * padN) {
        int j = i - padN;
        float s = 1e30f;
        if (j < nY) {
            s = 0.f;
            const float4* p = (const float4*)(Y + (size_t)j * D);
#pragma unroll
            for (int c = 0; c < D / 4; ++c) {
                float4 v = p[c];
                s += v.x * v.x + v.y * v.y + v.z * v.z + v.w * v.w;
            }
        }
        ny[j] = s;
    }
}

// ---------------------------------------------------------------------------
// Gram-sum kernel: one 128x128 pair tile per block.
// z=0: xx (upper-tri blocks, weight 2 off-diag), z=1: yy, z=2: xy (full).
// LDS k-major [64][128] with XOR swizzle; 8x8 fp32 register micro-tile.
// ---------------------------------------------------------------------------
__launch_bounds__(256, 2)
__global__ void gram_kernel(const float* __restrict__ X, const float* __restrict__ Y,
                            const float* __restrict__ nx, const float* __restrict__ ny,
                            int nX, int nY, double* __restrict__ part) {
    __shared__ float As[D][TILE];
    __shared__ float Bs[D][TILE];

    const int z  = blockIdx.z;
    const int bi = blockIdx.x;   // A-tile (i rows)
    const int bj = blockIdx.y;   // B-tile (j rows)
    if (z < 2 && bj < bi) return;   // symmetry: only upper triangle for xx/yy

    const float* Aptr; const float* Bptr; const float* nA; const float* nB;
    int rA, rB;
    if (z == 0)      { Aptr = X; Bptr = X; nA = nx; nB = nx; rA = nX; rB = nX; }
    else if (z == 1) { Aptr = Y; Bptr = Y; nA = ny; nB = ny; rA = nY; rB = nY; }
    else             { Aptr = X; Bptr = Y; nA = nx; nB = ny; rA = nX; rB = nY; }

    const int a0 = bi * TILE;
    const int b0 = bj * TILE;
    if (a0 >= rA || b0 >= rB) return;

    const int tid = threadIdx.x;

    // ---- stage A & B tiles into LDS, k-major, XOR-swizzled ----
#pragma unroll
    for (int c = 0; c < 8; ++c) {
        int idx = tid + 256 * c;        // 0..2047
        int row = idx >> 4;             // 0..127
        int kc  = idx & 15;             // float4 chunk along k
        int sw  = row ^ ((kc & 7) << 2);

        float4 va = make_float4(0.f, 0.f, 0.f, 0.f);
        int ga = a0 + row;
        if (ga < rA) va = *(const float4*)(Aptr + (size_t)ga * D + kc * 4);
        As[kc * 4 + 0][sw] = va.x;
        As[kc * 4 + 1][sw] = va.y;
        As[kc * 4 + 2][sw] = va.z;
        As[kc * 4 + 3][sw] = va.w;

        float4 vb = make_float4(0.f, 0.f, 0.f, 0.f);
        int gb = b0 + row;
        if (gb < rB) vb = *(const float4*)(Bptr + (size_t)gb * D + kc * 4);
        Bs[kc * 4 + 0][sw] = vb.x;
        Bs[kc * 4 + 1][sw] = vb.y;
        Bs[kc * 4 + 2][sw] = vb.z;
        Bs[kc * 4 + 3][sw] = vb.w;
    }
    __syncthreads();

    const int tx = tid & 15;    // m-direction (A rows)
    const int ty = tid >> 4;    // n-direction (B rows)

    float acc[8][8];
#pragma unroll
    for (int i = 0; i < 8; ++i)
#pragma unroll
        for (int j = 0; j < 8; ++j) acc[i][j] = 0.f;

#pragma unroll 8
    for (int k = 0; k < D; ++k) {
        int colA = (tx ^ ((k >> 2) & 7)) << 2;   // multiple of 4 -> ds_read_b128
        int colB = (ty ^ ((k >> 2) & 7)) << 2;
        float4 A0 = *(const float4*)&As[k][colA];
        float4 A1 = *(const float4*)&As[k][colA + 64];
        float4 B0 = *(const float4*)&Bs[k][colB];
        float4 B1 = *(const float4*)&Bs[k][colB + 64];
        float a[8] = {A0.x, A0.y, A0.z, A0.w, A1.x, A1.y, A1.z, A1.w};
        float b[8] = {B0.x, B0.y, B0.z, B0.w, B1.x, B1.y, B1.z, B1.w};
#pragma unroll
        for (int i = 0; i < 8; ++i)
#pragma unroll
            for (int j = 0; j < 8; ++j)
                acc[i][j] = fmaf(a[i], b[j], acc[i][j]);
    }

    // ---- epilogue: sq = na + nb - 2*dot, exp, local sum ----
    float na[8], nb[8];
#pragma unroll
    for (int i = 0; i < 8; ++i) {
        int m = (i < 4) ? (4 * tx + i) : (60 + 4 * tx + i);   // 64 + 4tx + (i-4)
        int n = (i < 4) ? (4 * ty + i) : (60 + 4 * ty + i);
        na[i] = nA[a0 + m];
        nb[i] = nB[b0 + n];
    }

    const float C = -0.72134752044448170367f;   // -log2(e) / (2*sigma^2), sigma=1
    float local = 0.f;
#pragma unroll
    for (int i = 0; i < 8; ++i)
#pragma unroll
        for (int j = 0; j < 8; ++j) {
            float sq = na[i] + nb[j] - 2.f * acc[i][j];
            sq = fmaxf(sq, 0.f);
            local += __builtin_amdgcn_exp2f(sq * C);
        }

    if (z < 2 && bj != bi) local *= 2.f;   // symmetric off-diagonal blocks

    // ---- block reduction -> double atomic ----
#pragma unroll
    for (int m = 32; m > 0; m >>= 1) local += __shfl_xor(local, m, 64);

    __syncthreads();                       // done reading As; reuse for reduction
    if ((tid & 63) == 0) As[0][tid >> 6] = local;
    __syncthreads();
    if (tid == 0) {
        float s = As[0][0] + As[0][1] + As[0][2] + As[0][3];
        atomicAdd(&part[z], (double)s);
    }
}

__global__ void combine_kernel(const double* __restrict__ part, float* __restrict__ out,
                               int nX, int nY) {
    double xx = part[0], yy = part[1], xy = part[2];
    double r = xx / ((double)nX * (double)nX)
             + yy / ((double)nY * (double)nY)
             - 2.0 * xy / ((double)nX * (double)nY);
    out[0] = (float)r;
}

extern "C" void kernel_launch(void* const* d_in, const int* in_sizes, int n_in,
                              void* d_out, int out_size, void* d_ws, size_t ws_size,
                              hipStream_t stream) {
    const float* X = (const float*)d_in[0];
    const float* Y = (const float*)d_in[1];
    const int nX = in_sizes[0] / D;
    const int nY = in_sizes[1] / D;
    const int nMax = nX > nY ? nX : nY;
    const int NT   = (nMax + TILE - 1) / TILE;
    const int padN = NT * TILE;

    // ws layout: [0,24): double part[3]; [64, ...): norm_x[padN], norm_y[padN]
    double* part = (double*)d_ws;
    float*  nx   = (float*)((char*)d_ws + 64);
    float*  ny   = nx + padN;

    hipMemsetAsync(d_ws, 0, 64, stream);

    int tn = 2 * padN;
    norms_kernel<<<(tn + 255) / 256, 256, 0, stream>>>(X, Y, nx, ny, nX, nY, padN);

    dim3 grid(NT, NT, 3);
    gram_kernel<<<grid, 256, 0, stream>>>(X, Y, nx, ny, nX, nY, part);

    combine_kernel<<<1, 1, 0, stream>>>(part, (float*)d_out, nX, nY);
}

// Round 2
// 275.736 us; speedup vs baseline: 4.8959x; 4.8959x over previous
//
#include <hip/hip_runtime.h>

#define D 64
#define TILE 128

typedef __attribute__((ext_vector_type(8))) short short8;
typedef __attribute__((ext_vector_type(4))) float f32x4;
typedef __attribute__((ext_vector_type(8))) unsigned short ushort8;

#define CC    (-0.7213475204444817f)   // -log2(e)/(2*sigma^2), sigma=1
#define NEG2C ( 1.4426950408889634f)   // -2*CC

// ---------------------------------------------------------------------------
// Prep: fp32 -> bf16 (RNE) copy, pre-swizzled within each 128B row
// (chunk' = chunk ^ (row&7), chunk = 8 bf16 = 16B), plus fp32 row norms.
// Padded rows (row >= n): zeros + norm 1e30 (=> exp term 0, free masking).
// One thread per 16B output chunk; 8 threads per row reduce norm via shfl.
// ---------------------------------------------------------------------------
__global__ void prep_kernel(const float* __restrict__ X, const float* __restrict__ Y,
                            unsigned short* __restrict__ Xbf, unsigned short* __restrict__ Ybf,
                            float* __restrict__ nx, float* __restrict__ ny,
                            int nX, int nY, int padN) {
    int t = blockIdx.x * blockDim.x + threadIdx.x;
    int half = padN * 8;
    if (t >= 2 * half) return;

    const float* src; unsigned short* dst; float* nrm; int n; int tt;
    if (t < half) { src = X; dst = Xbf; nrm = nx; n = nX; tt = t; }
    else          { src = Y; dst = Ybf; nrm = ny; n = nY; tt = t - half; }

    int row = tt >> 3, c8 = tt & 7;

    float v[8];
    float ss = 0.f;
    if (row < n) {
        const float4* p = (const float4*)(src + (size_t)row * D + c8 * 8);
        float4 f0 = p[0], f1 = p[1];
        v[0] = f0.x; v[1] = f0.y; v[2] = f0.z; v[3] = f0.w;
        v[4] = f1.x; v[5] = f1.y; v[6] = f1.z; v[7] = f1.w;
#pragma unroll
        for (int i = 0; i < 8; ++i) ss += v[i] * v[i];
    } else {
#pragma unroll
        for (int i = 0; i < 8; ++i) v[i] = 0.f;
    }

    // row-norm: reduce over the 8 chunk-threads of this row (aligned within wave)
    ss += __shfl_xor(ss, 1, 64);
    ss += __shfl_xor(ss, 2, 64);
    ss += __shfl_xor(ss, 4, 64);

    ushort8 o;
#pragma unroll
    for (int i = 0; i < 8; ++i) {
        unsigned u = __float_as_uint(v[i]);
        o[i] = (unsigned short)((u + 0x7fffu + ((u >> 16) & 1u)) >> 16);   // RNE to bf16
    }
    *(ushort8*)(dst + (size_t)row * D + ((c8 ^ (row & 7)) << 3)) = o;

    if (c8 == 0) nrm[row] = (row < n) ? ss : 1e30f;
}

// ---------------------------------------------------------------------------
// Gram-sum: one 128x128 pair tile per block, 4 waves, each wave a 64x64
// sub-tile via 16 fragments of mfma_f32_16x16x32_bf16 (2 k-steps over K=64).
// z=0: xx (upper-tri, x2 off-diag), z=1: yy, z=2: xy (full).
// Tiles staged bf16 via global_load_lds width 16 (source pre-swizzled, LDS
// linear, reads apply the same XOR -> conflict-free per rule 21).
// Epilogue: term = exp2(min(NEG2C*dot + C*(na+nb), 0)); diagonal forced to 1.
// ---------------------------------------------------------------------------
__launch_bounds__(256, 2)
__global__ void gram_kernel(const unsigned short* __restrict__ Xbf,
                            const unsigned short* __restrict__ Ybf,
                            const float* __restrict__ nx, const float* __restrict__ ny,
                            int nX, int nY, int NT, float* __restrict__ part) {
    __shared__ unsigned short Abuf[TILE * D];   // 16 KB, rows pre-swizzled
    __shared__ unsigned short Bbuf[TILE * D];   // 16 KB
    __shared__ float red[4];

    const int z  = blockIdx.z;
    const int bi = blockIdx.x;     // A-tile
    const int bj = blockIdx.y;     // B-tile
    const int lin = (z * NT + bj) * NT + bi;
    const int tid = threadIdx.x;

    if (z < 2 && bj < bi) {        // symmetry: skip lower triangle
        if (tid == 0) part[lin] = 0.f;
        return;
    }

    const unsigned short* Abase; const unsigned short* Bbase;
    const float* nA; const float* nB; int rA;
    if (z == 0)      { Abase = Xbf; Bbase = Xbf; nA = nx; nB = nx; rA = nX; }
    else if (z == 1) { Abase = Ybf; Bbase = Ybf; nA = ny; nB = ny; rA = nY; }
    else             { Abase = Xbf; Bbase = Ybf; nA = nx; nB = ny; rA = nX; }

    const int a0 = bi * TILE;
    const int b0 = bj * TILE;

    const int w = tid >> 6, lane = tid & 63;

    // ---- stage A & B tiles (each 16 KB contiguous) into LDS ----
    {
        const char* As = (const char*)(Abase + (size_t)a0 * D);
        const char* Bs = (const char*)(Bbase + (size_t)b0 * D);
#pragma unroll
        for (int c = 0; c < 4; ++c) {
            int off = w * 4096 + c * 1024;
            __builtin_amdgcn_global_load_lds(
                (const __attribute__((address_space(1))) void*)(As + off + lane * 16),
                (__attribute__((address_space(3))) void*)((char*)Abuf + off), 16, 0, 0);
            __builtin_amdgcn_global_load_lds(
                (const __attribute__((address_space(1))) void*)(Bs + off + lane * 16),
                (__attribute__((address_space(3))) void*)((char*)Bbuf + off), 16, 0, 0);
        }
    }
    __syncthreads();

    // ---- MFMA: wave w owns 64x64 sub-tile at (wm, wn) ----
    const int wm = (w & 1) * 64, wn = (w >> 1) * 64;
    const int lhi = lane >> 4, llo = lane & 15;

    f32x4 acc[4][4];
#pragma unroll
    for (int fm = 0; fm < 4; ++fm)
#pragma unroll
        for (int fn = 0; fn < 4; ++fn) acc[fm][fn] = (f32x4)(0.f);

#pragma unroll
    for (int ks = 0; ks < 2; ++ks) {
        short8 af[4], bfr[4];
        const int ck = ks * 4 + lhi;
#pragma unroll
        for (int fm = 0; fm < 4; ++fm) {
            int r = wm + fm * 16 + llo;
            af[fm] = *(const short8*)&Abuf[r * D + ((ck ^ (r & 7)) << 3)];
        }
#pragma unroll
        for (int fn = 0; fn < 4; ++fn) {
            int r = wn + fn * 16 + llo;
            bfr[fn] = *(const short8*)&Bbuf[r * D + ((ck ^ (r & 7)) << 3)];
        }
#pragma unroll
        for (int fm = 0; fm < 4; ++fm)
#pragma unroll
            for (int fn = 0; fn < 4; ++fn)
                acc[fm][fn] = __builtin_amdgcn_mfma_f32_16x16x32_bf16(
                    af[fm], bfr[fn], acc[fm][fn], 0, 0, 0);
    }

    // ---- epilogue ----
    // C/D layout (16x16x32): col = lane&15, row = (lane>>4)*4 + reg
    float u[4][4], vv[4];
#pragma unroll
    for (int fm = 0; fm < 4; ++fm)
#pragma unroll
        for (int r = 0; r < 4; ++r)
            u[fm][r] = CC * nA[a0 + wm + fm * 16 + lhi * 4 + r];
#pragma unroll
    for (int fn = 0; fn < 4; ++fn)
        vv[fn] = CC * nB[b0 + wn + fn * 16 + llo];

    float local = 0.f;
    const bool diag = (z < 2) && (bi == bj);
    if (diag) {
#pragma unroll
        for (int fm = 0; fm < 4; ++fm)
#pragma unroll
            for (int fn = 0; fn < 4; ++fn)
#pragma unroll
                for (int r = 0; r < 4; ++r) {
                    float arg = fminf(fmaf(NEG2C, acc[fm][fn][r], u[fm][r] + vv[fn]), 0.f);
                    float term = __builtin_amdgcn_exp2f(arg);
                    int gm = wm + fm * 16 + lhi * 4 + r;
                    int gn = wn + fn * 16 + llo;
                    if (gm == gn && a0 + gm < rA) term = 1.0f;   // exact diagonal
                    local += term;
                }
    } else {
#pragma unroll
        for (int fm = 0; fm < 4; ++fm)
#pragma unroll
            for (int fn = 0; fn < 4; ++fn)
#pragma unroll
                for (int r = 0; r < 4; ++r) {
                    float arg = fminf(fmaf(NEG2C, acc[fm][fn][r], u[fm][r] + vv[fn]), 0.f);
                    local += __builtin_amdgcn_exp2f(arg);
                }
        if (z < 2) local *= 2.f;   // symmetric off-diagonal tile
    }

    // ---- block reduction -> per-block partial (no atomics) ----
#pragma unroll
    for (int m = 32; m > 0; m >>= 1) local += __shfl_xor(local, m, 64);
    if (lane == 0) red[w] = local;
    __syncthreads();
    if (tid == 0) part[lin] = red[0] + red[1] + red[2] + red[3];
}

// ---------------------------------------------------------------------------
// Final reduce: sum per-block partials (double), combine MMD.
// ---------------------------------------------------------------------------
__global__ void reduce_kernel(const float* __restrict__ part, float* __restrict__ out,
                              int NT, int nX, int nY) {
    __shared__ double sh[3][4];
    const int tid = threadIdx.x;
    const int n2 = NT * NT;
    double s0 = 0, s1 = 0, s2 = 0;
    for (int i = tid; i < n2; i += 256) {
        s0 += (double)part[i];
        s1 += (double)part[n2 + i];
        s2 += (double)part[2 * n2 + i];
    }
#pragma unroll
    for (int m = 32; m > 0; m >>= 1) {
        s0 += __shfl_xor(s0, m, 64);
        s1 += __shfl_xor(s1, m, 64);
        s2 += __shfl_xor(s2, m, 64);
    }
    const int w = tid >> 6, lane = tid & 63;
    if (lane == 0) { sh[0][w] = s0; sh[1][w] = s1; sh[2][w] = s2; }
    __syncthreads();
    if (tid == 0) {
        double xx = sh[0][0] + sh[0][1] + sh[0][2] + sh[0][3];
        double yy = sh[1][0] + sh[1][1] + sh[1][2] + sh[1][3];
        double xy = sh[2][0] + sh[2][1] + sh[2][2] + sh[2][3];
        out[0] = (float)(xx / ((double)nX * (double)nX)
                       + yy / ((double)nY * (double)nY)
                       - 2.0 * xy / ((double)nX * (double)nY));
    }
}

extern "C" void kernel_launch(void* const* d_in, const int* in_sizes, int n_in,
                              void* d_out, int out_size, void* d_ws, size_t ws_size,
                              hipStream_t stream) {
    const float* X = (const float*)d_in[0];
    const float* Y = (const float*)d_in[1];
    const int nX = in_sizes[0] / D;
    const int nY = in_sizes[1] / D;
    const int nMax = nX > nY ? nX : nY;
    const int NT   = (nMax + TILE - 1) / TILE;
    const int padN = NT * TILE;

    // ws layout (256B-aligned sections):
    //   part[3*NT*NT] f32 | nx[padN] f32 | ny[padN] f32 | Xbf[padN*64] bf16 | Ybf[padN*64] bf16
    char* ws = (char*)d_ws;
    size_t off = 0;
    float* part = (float*)(ws + off); off += ((size_t)3 * NT * NT * 4 + 255) & ~(size_t)255;
    float* nxp  = (float*)(ws + off); off += ((size_t)padN * 4 + 255) & ~(size_t)255;
    float* nyp  = (float*)(ws + off); off += ((size_t)padN * 4 + 255) & ~(size_t)255;
    unsigned short* Xbf = (unsigned short*)(ws + off); off += ((size_t)padN * D * 2 + 255) & ~(size_t)255;
    unsigned short* Ybf = (unsigned short*)(ws + off);

    int chunks = 2 * padN * 8;
    prep_kernel<<<(chunks + 255) / 256, 256, 0, stream>>>(X, Y, Xbf, Ybf, nxp, nyp, nX, nY, padN);

    dim3 grid(NT, NT, 3);
    gram_kernel<<<grid, 256, 0, stream>>>(Xbf, Ybf, nxp, nyp, nX, nY, NT, part);

    reduce_kernel<<<1, 256, 0, stream>>>(part, (float*)d_out, NT, nX, nY);
}

// Round 3
// 170.426 us; speedup vs baseline: 7.9212x; 1.6179x over previous
//
#include <hip/hip_runtime.h>

#define D 64
#define TILE 128

typedef __attribute__((ext_vector_type(8))) short short8;
typedef __attribute__((ext_vector_type(4))) float f32x4;
typedef __attribute__((ext_vector_type(8))) unsigned short ushort8;

#define CC     (-0.7213475204444817f)   // -log2(e)/(2*sigma^2), sigma=1
#define SCALE  (1.2011224087864498f)    // sqrt(2*log2(e)); dot(scaled) = -2C*dot
#define THR    (-28.0f)                 // terms < 2^-28 dropped: total mass < 3.0 -> <7.5e-9 on output

// ---------------------------------------------------------------------------
// Prep: fp32 -> bf16 (RNE) copy, PRE-SCALED by sqrt(2*log2 e), pre-swizzled
// within each 128B row (chunk' = chunk ^ (row&7), chunk = 8 bf16 = 16B).
// Norms stored PRE-MULTIPLIED by C (fp32, from unscaled data).
// Padded rows: zeros + C*1e30 (=> arg -huge -> term 0, free masking).
// ---------------------------------------------------------------------------
__global__ void prep_kernel(const float* __restrict__ X, const float* __restrict__ Y,
                            unsigned short* __restrict__ Xbf, unsigned short* __restrict__ Ybf,
                            float* __restrict__ nx, float* __restrict__ ny,
                            int nX, int nY, int padN) {
    int t = blockIdx.x * blockDim.x + threadIdx.x;
    int half = padN * 8;
    if (t >= 2 * half) return;

    const float* src; unsigned short* dst; float* nrm; int n; int tt;
    if (t < half) { src = X; dst = Xbf; nrm = nx; n = nX; tt = t; }
    else          { src = Y; dst = Ybf; nrm = ny; n = nY; tt = t - half; }

    int row = tt >> 3, c8 = tt & 7;

    float v[8];
    float ss = 0.f;
    if (row < n) {
        const float4* p = (const float4*)(src + (size_t)row * D + c8 * 8);
        float4 f0 = p[0], f1 = p[1];
        v[0] = f0.x; v[1] = f0.y; v[2] = f0.z; v[3] = f0.w;
        v[4] = f1.x; v[5] = f1.y; v[6] = f1.z; v[7] = f1.w;
#pragma unroll
        for (int i = 0; i < 8; ++i) ss += v[i] * v[i];
    } else {
#pragma unroll
        for (int i = 0; i < 8; ++i) v[i] = 0.f;
    }

    // row-norm: reduce over the 8 chunk-threads of this row
    ss += __shfl_xor(ss, 1, 64);
    ss += __shfl_xor(ss, 2, 64);
    ss += __shfl_xor(ss, 4, 64);

    ushort8 o;
#pragma unroll
    for (int i = 0; i < 8; ++i) {
        unsigned u = __float_as_uint(v[i] * SCALE);
        o[i] = (unsigned short)((u + 0x7fffu + ((u >> 16) & 1u)) >> 16);   // RNE to bf16
    }
    *(ushort8*)(dst + (size_t)row * D + ((c8 ^ (row & 7)) << 3)) = o;

    if (c8 == 0) nrm[row] = (row < n) ? (CC * ss) : (CC * 1e30f);
}

// ---------------------------------------------------------------------------
// Gram-sum: one 128x128 pair tile per block, 4 waves, each a 64x64 sub-tile
// via mfma_f32_16x16x32_bf16. Accumulator INITIALIZED to C*(n_i+n_j); inputs
// pre-scaled so MFMA output IS the exp2 argument. Fast path: per-thread max
// of 64 args + one __any branch -> skip all exp work unless a near pair
// exists in the tile (prob ~1% for random data; bound-safe for any data).
// z=0: xx (upper-tri, x2 off-diag), z=1: yy, z=2: xy (full).
// ---------------------------------------------------------------------------
__launch_bounds__(256, 4)
__global__ void gram_kernel(const unsigned short* __restrict__ Xbf,
                            const unsigned short* __restrict__ Ybf,
                            const float* __restrict__ nx, const float* __restrict__ ny,
                            int nX, int nY, int NT, float* __restrict__ part) {
    __shared__ unsigned short Abuf[TILE * D];   // 16 KB, rows pre-swizzled
    __shared__ unsigned short Bbuf[TILE * D];   // 16 KB
    __shared__ float red[4];

    const int z  = blockIdx.z;
    const int bi = blockIdx.x;
    const int bj = blockIdx.y;
    const int lin = (z * NT + bj) * NT + bi;
    const int tid = threadIdx.x;

    if (z < 2 && bj < bi) {        // symmetry: skip lower triangle
        if (tid == 0) part[lin] = 0.f;
        return;
    }

    const unsigned short* Abase; const unsigned short* Bbase;
    const float* nA; const float* nB; int rA;
    if (z == 0)      { Abase = Xbf; Bbase = Xbf; nA = nx; nB = nx; rA = nX; }
    else if (z == 1) { Abase = Ybf; Bbase = Ybf; nA = ny; nB = ny; rA = nY; }
    else             { Abase = Xbf; Bbase = Ybf; nA = nx; nB = ny; rA = nX; }

    const int a0 = bi * TILE;
    const int b0 = bj * TILE;

    const int w = tid >> 6, lane = tid & 63;

    // ---- stage A & B tiles (each 16 KB contiguous) into LDS ----
    {
        const char* As = (const char*)(Abase + (size_t)a0 * D);
        const char* Bs = (const char*)(Bbase + (size_t)b0 * D);
#pragma unroll
        for (int c = 0; c < 4; ++c) {
            int off = w * 4096 + c * 1024;
            __builtin_amdgcn_global_load_lds(
                (const __attribute__((address_space(1))) void*)(As + off + lane * 16),
                (__attribute__((address_space(3))) void*)((char*)Abuf + off), 16, 0, 0);
            __builtin_amdgcn_global_load_lds(
                (const __attribute__((address_space(1))) void*)(Bs + off + lane * 16),
                (__attribute__((address_space(3))) void*)((char*)Bbuf + off), 16, 0, 0);
        }
    }

    // ---- norm loads (overlap the staging latency) + acc init ----
    const int wm = (w & 1) * 64, wn = (w >> 1) * 64;
    const int lhi = lane >> 4, llo = lane & 15;

    float uA[4][4], vB[4];
#pragma unroll
    for (int fm = 0; fm < 4; ++fm)
#pragma unroll
        for (int r = 0; r < 4; ++r)
            uA[fm][r] = nA[a0 + wm + fm * 16 + lhi * 4 + r];   // already *C
#pragma unroll
    for (int fn = 0; fn < 4; ++fn)
        vB[fn] = nB[b0 + wn + fn * 16 + llo];                  // already *C

    f32x4 acc[4][4];
#pragma unroll
    for (int fm = 0; fm < 4; ++fm)
#pragma unroll
        for (int fn = 0; fn < 4; ++fn)
#pragma unroll
            for (int r = 0; r < 4; ++r)
                acc[fm][fn][r] = uA[fm][r] + vB[fn];           // C*(n_i+n_j)

    __syncthreads();

    // ---- MFMA: wave w owns 64x64 sub-tile at (wm, wn) ----
#pragma unroll
    for (int ks = 0; ks < 2; ++ks) {
        short8 af[4], bfr[4];
        const int ck = ks * 4 + lhi;
#pragma unroll
        for (int fm = 0; fm < 4; ++fm) {
            int r = wm + fm * 16 + llo;
            af[fm] = *(const short8*)&Abuf[r * D + ((ck ^ (r & 7)) << 3)];
        }
#pragma unroll
        for (int fn = 0; fn < 4; ++fn) {
            int r = wn + fn * 16 + llo;
            bfr[fn] = *(const short8*)&Bbuf[r * D + ((ck ^ (r & 7)) << 3)];
        }
#pragma unroll
        for (int fm = 0; fm < 4; ++fm)
#pragma unroll
            for (int fn = 0; fn < 4; ++fn)
                acc[fm][fn] = __builtin_amdgcn_mfma_f32_16x16x32_bf16(
                    af[fm], bfr[fn], acc[fm][fn], 0, 0, 0);
    }
    // acc[fm][fn][r] is now the exp2 argument: C*(n_i+n_j) - 2C*dot = C*sq

    // ---- epilogue ----
    float local = 0.f;
    const bool diag = (z < 2) && (bi == bj);
    if (diag) {
        // full path with exact diagonal (313 tiles total -> negligible)
#pragma unroll
        for (int fm = 0; fm < 4; ++fm)
#pragma unroll
            for (int fn = 0; fn < 4; ++fn)
#pragma unroll
                for (int r = 0; r < 4; ++r) {
                    float term = __builtin_amdgcn_exp2f(fminf(acc[fm][fn][r], 0.f));
                    int gm = wm + fm * 16 + lhi * 4 + r;
                    int gn = wn + fn * 16 + llo;
                    if (gm == gn && a0 + gm < rA) term = 1.0f;
                    local += term;
                }
    } else {
        // fast path: per-thread max, one branch; exp only if a near pair exists
        float mx = -3.4e38f;
#pragma unroll
        for (int fm = 0; fm < 4; ++fm)
#pragma unroll
            for (int fn = 0; fn < 4; ++fn) {
                f32x4 a = acc[fm][fn];
                mx = fmaxf(mx, fmaxf(fmaxf(a[0], a[1]), fmaxf(a[2], a[3])));
            }
        if (__any(mx > THR)) {
#pragma unroll
            for (int fm = 0; fm < 4; ++fm)
#pragma unroll
                for (int fn = 0; fn < 4; ++fn)
#pragma unroll
                    for (int r = 0; r < 4; ++r)
                        local += __builtin_amdgcn_exp2f(fminf(acc[fm][fn][r], 0.f));
        }
        if (z < 2) local *= 2.f;   // symmetric off-diagonal tile
    }

    // ---- block reduction -> per-block partial (no atomics) ----
#pragma unroll
    for (int m = 32; m > 0; m >>= 1) local += __shfl_xor(local, m, 64);
    if (lane == 0) red[w] = local;
    __syncthreads();
    if (tid == 0) part[lin] = red[0] + red[1] + red[2] + red[3];
}

// ---------------------------------------------------------------------------
// Final reduce: sum per-block partials (double), combine MMD.
// ---------------------------------------------------------------------------
__global__ void reduce_kernel(const float* __restrict__ part, float* __restrict__ out,
                              int NT, int nX, int nY) {
    __shared__ double sh[3][4];
    const int tid = threadIdx.x;
    const int n2 = NT * NT;
    double s0 = 0, s1 = 0, s2 = 0;
    for (int i = tid; i < n2; i += 256) {
        s0 += (double)part[i];
        s1 += (double)part[n2 + i];
        s2 += (double)part[2 * n2 + i];
    }
#pragma unroll
    for (int m = 32; m > 0; m >>= 1) {
        s0 += __shfl_xor(s0, m, 64);
        s1 += __shfl_xor(s1, m, 64);
        s2 += __shfl_xor(s2, m, 64);
    }
    const int w = tid >> 6, lane = tid & 63;
    if (lane == 0) { sh[0][w] = s0; sh[1][w] = s1; sh[2][w] = s2; }
    __syncthreads();
    if (tid == 0) {
        double xx = sh[0][0] + sh[0][1] + sh[0][2] + sh[0][3];
        double yy = sh[1][0] + sh[1][1] + sh[1][2] + sh[1][3];
        double xy = sh[2][0] + sh[2][1] + sh[2][2] + sh[2][3];
        out[0] = (float)(xx / ((double)nX * (double)nX)
                       + yy / ((double)nY * (double)nY)
                       - 2.0 * xy / ((double)nX * (double)nY));
    }
}

extern "C" void kernel_launch(void* const* d_in, const int* in_sizes, int n_in,
                              void* d_out, int out_size, void* d_ws, size_t ws_size,
                              hipStream_t stream) {
    const float* X = (const float*)d_in[0];
    const float* Y = (const float*)d_in[1];
    const int nX = in_sizes[0] / D;
    const int nY = in_sizes[1] / D;
    const int nMax = nX > nY ? nX : nY;
    const int NT   = (nMax + TILE - 1) / TILE;
    const int padN = NT * TILE;

    // ws layout (256B-aligned sections):
    //   part[3*NT*NT] f32 | nx[padN] f32 | ny[padN] f32 | Xbf[padN*64] bf16 | Ybf[padN*64] bf16
    char* ws = (char*)d_ws;
    size_t off = 0;
    float* part = (float*)(ws + off); off += ((size_t)3 * NT * NT * 4 + 255) & ~(size_t)255;
    float* nxp  = (float*)(ws + off); off += ((size_t)padN * 4 + 255) & ~(size_t)255;
    float* nyp  = (float*)(ws + off); off += ((size_t)padN * 4 + 255) & ~(size_t)255;
    unsigned short* Xbf = (unsigned short*)(ws + off); off += ((size_t)padN * D * 2 + 255) & ~(size_t)255;
    unsigned short* Ybf = (unsigned short*)(ws + off);

    int chunks = 2 * padN * 8;
    prep_kernel<<<(chunks + 255) / 256, 256, 0, stream>>>(X, Y, Xbf, Ybf, nxp, nyp, nX, nY, padN);

    dim3 grid(NT, NT, 3);
    gram_kernel<<<grid, 256, 0, stream>>>(Xbf, Ybf, nxp, nyp, nX, nY, NT, part);

    reduce_kernel<<<1, 256, 0, stream>>>(part, (float*)d_out, NT, nX, nY);
}

// Round 4
// 128.635 us; speedup vs baseline: 10.4946x; 1.3249x over previous
//
#include <hip/hip_runtime.h>

#define D 64
#define TILE 128
#define W 16            // B-tiles per block (chunk length)

typedef __attribute__((ext_vector_type(8))) short short8;
typedef __attribute__((ext_vector_type(4))) float f32x4;
typedef __attribute__((ext_vector_type(8))) unsigned short ushort8;

#define CC     (-0.7213475204444817f)   // -log2(e)/(2*sigma^2), sigma=1
#define SCALE  (1.2011224087864498f)    // sqrt(2*log2(e)); dot(scaled) = -2C*dot
#define THR    (-28.0f)                 // drop terms < 2^-28: total mass < 3 -> <1e-8 on output

// ---------------------------------------------------------------------------
// Prep: fp32 -> bf16 (RNE), PRE-SCALED by sqrt(2*log2 e), pre-swizzled within
// each 128B row (chunk' = chunk ^ (row&7), chunk = 8 bf16 = 16B).
// Norms stored PRE-MULTIPLIED by C. Padded rows: zeros + C*1e30.
// ---------------------------------------------------------------------------
__global__ void prep_kernel(const float* __restrict__ X, const float* __restrict__ Y,
                            unsigned short* __restrict__ Xbf, unsigned short* __restrict__ Ybf,
                            float* __restrict__ nx, float* __restrict__ ny,
                            int nX, int nY, int padN) {
    int t = blockIdx.x * blockDim.x + threadIdx.x;
    int half = padN * 8;
    if (t >= 2 * half) return;

    const float* src; unsigned short* dst; float* nrm; int n; int tt;
    if (t < half) { src = X; dst = Xbf; nrm = nx; n = nX; tt = t; }
    else          { src = Y; dst = Ybf; nrm = ny; n = nY; tt = t - half; }

    int row = tt >> 3, c8 = tt & 7;

    float v[8];
    float ss = 0.f;
    if (row < n) {
        const float4* p = (const float4*)(src + (size_t)row * D + c8 * 8);
        float4 f0 = p[0], f1 = p[1];
        v[0] = f0.x; v[1] = f0.y; v[2] = f0.z; v[3] = f0.w;
        v[4] = f1.x; v[5] = f1.y; v[6] = f1.z; v[7] = f1.w;
#pragma unroll
        for (int i = 0; i < 8; ++i) ss += v[i] * v[i];
    } else {
#pragma unroll
        for (int i = 0; i < 8; ++i) v[i] = 0.f;
    }

    ss += __shfl_xor(ss, 1, 64);
    ss += __shfl_xor(ss, 2, 64);
    ss += __shfl_xor(ss, 4, 64);

    ushort8 o;
#pragma unroll
    for (int i = 0; i < 8; ++i) {
        unsigned u = __float_as_uint(v[i] * SCALE);
        o[i] = (unsigned short)((u + 0x7fffu + ((u >> 16) & 1u)) >> 16);   // RNE
    }
    *(ushort8*)(dst + (size_t)row * D + ((c8 ^ (row & 7)) << 3)) = o;

    if (c8 == 0) nrm[row] = (row < n) ? (CC * ss) : (CC * 1e30f);
}

// ---------------------------------------------------------------------------
// Stage one 16KB B-tile (bf16, pre-swizzled rows) to LDS, linear dest.
// 4 global_load_lds dwordx4 per wave (1KB each x 4 waves x 4 = 16KB).
// ---------------------------------------------------------------------------
__device__ static inline void stage_tile(const char* src, char* dst, int w, int lane) {
#pragma unroll
    for (int cIdx = 0; cIdx < 4; ++cIdx) {
        int off = w * 4096 + cIdx * 1024;
        __builtin_amdgcn_global_load_lds(
            (const __attribute__((address_space(1))) void*)(src + off + lane * 16),
            (__attribute__((address_space(3))) void*)(dst + off), 16, 0, 0);
    }
}

// ---------------------------------------------------------------------------
// Persistent-A gram kernel. Block = (chunk c, A-row bi, z). A-panel fragments
// live in registers for the whole block (loaded straight from global, L2-hot);
// B-tiles double-buffered in LDS with counted vmcnt(8) so stage(t+1) + v-norm
// prefetch stay in flight across raw s_barriers (no full drain per tile).
// z=0: xx (bj>=bi, x2 off-diag), z=1: yy, z=2: xy (full rows).
// ---------------------------------------------------------------------------
__launch_bounds__(256, 3)
__global__ void gram_kernel(const unsigned short* __restrict__ Xbf,
                            const unsigned short* __restrict__ Ybf,
                            const float* __restrict__ nx, const float* __restrict__ ny,
                            int nX, int nY, int NT, int CH, float* __restrict__ part) {
    __shared__ unsigned short Bbuf[2][TILE * D];   // 2 x 16KB
    __shared__ float red[4];

    const int c   = blockIdx.x;
    const int bi  = blockIdx.y;
    const int z   = blockIdx.z;
    const int tid = threadIdx.x;
    const int lin = (z * NT + bi) * CH + c;

    const int bj0 = (z < 2 ? bi : 0) + c * W;
    int ntiles = NT - bj0; if (ntiles > W) ntiles = W;
    if (ntiles <= 0) { if (tid == 0) part[lin] = 0.f; return; }

    const unsigned short* Abase; const unsigned short* Bbase;
    const float* nA; const float* nB; int rA;
    if (z == 0)      { Abase = Xbf; Bbase = Xbf; nA = nx; nB = nx; rA = nX; }
    else if (z == 1) { Abase = Ybf; Bbase = Ybf; nA = ny; nB = ny; rA = nY; }
    else             { Abase = Xbf; Bbase = Ybf; nA = nx; nB = ny; rA = nX; }

    const int a0 = bi * TILE;
    const int w = tid >> 6, lane = tid & 63;
    const int wm = (w & 1) * 64, wn = (w >> 1) * 64;
    const int lhi = lane >> 4, llo = lane & 15;
    const int sw = llo & 7;

    // ---------------- prologue ----------------
    const char* Bsrc = (const char*)(Bbase + (size_t)bj0 * TILE * D);   // +16KB/tile
    stage_tile(Bsrc, (char*)&Bbuf[0][0], w, lane);

    // v-norm for tile 0 (prefetched regs; per-lane col norms, already *C)
    const float* nBp = nB + (size_t)bj0 * TILE + wn + llo;
    float vcur[4], vnxt[4];
#pragma unroll
    for (int fn = 0; fn < 4; ++fn) vcur[fn] = nBp[fn * 16];

    // A fragments straight from global (strided 16B reads, L2-resident)
    const unsigned short* Ab = Abase + (size_t)(a0 + wm) * D;
    short8 af[2][4];
#pragma unroll
    for (int ks = 0; ks < 2; ++ks)
#pragma unroll
        for (int fm = 0; fm < 4; ++fm) {
            int r = fm * 16 + llo;
            af[ks][fm] = *(const short8*)&Ab[r * D + (((ks * 4 + lhi) ^ sw) << 3)];
        }

    // u-norms (A side), once per block
    float u[4][4];
#pragma unroll
    for (int fm = 0; fm < 4; ++fm)
#pragma unroll
        for (int rr = 0; rr < 4; ++rr)
            u[fm][rr] = nA[a0 + wm + fm * 16 + lhi * 4 + rr];

    const int bb0 = (lhi ^ sw) << 3;          // element offset, ks=0
    const int bb1 = ((4 + lhi) ^ sw) << 3;    // ks=1

    float local = 0.f;

    // ---------------- main loop over B-tiles ----------------
    for (int t = 0; t < ntiles; ++t) {
        const int cur = t & 1;

        if (t + 1 < ntiles) {
            stage_tile(Bsrc + (size_t)(t + 1) * TILE * D * 2, (char*)&Bbuf[cur ^ 1][0], w, lane);
#pragma unroll
            for (int fn = 0; fn < 4; ++fn) vnxt[fn] = nBp[(size_t)(t + 1) * TILE + fn * 16];
            // keep the 8 newest (stage(t+1) x4 + vnxt x4) in flight; drain older
            asm volatile("s_waitcnt vmcnt(8)" ::: "memory");
        } else {
            asm volatile("s_waitcnt vmcnt(0)" ::: "memory");
        }
        __builtin_amdgcn_s_barrier();          // B1: Bbuf[cur] ready

        // B fragments from LDS
        short8 bf0[4], bf1[4];
#pragma unroll
        for (int fn = 0; fn < 4; ++fn) {
            int r = (wn + fn * 16 + llo) * D;
            bf0[fn] = *(const short8*)&Bbuf[cur][r + bb0];
            bf1[fn] = *(const short8*)&Bbuf[cur][r + bb1];
        }

        // acc init = C*(n_i + n_j); MFMA adds -2C*dot -> acc = C*sq
        f32x4 acc[4][4];
#pragma unroll
        for (int fm = 0; fm < 4; ++fm)
#pragma unroll
            for (int fn = 0; fn < 4; ++fn)
#pragma unroll
                for (int rr = 0; rr < 4; ++rr)
                    acc[fm][fn][rr] = u[fm][rr] + vcur[fn];

#pragma unroll
        for (int fm = 0; fm < 4; ++fm)
#pragma unroll
            for (int fn = 0; fn < 4; ++fn) {
                acc[fm][fn] = __builtin_amdgcn_mfma_f32_16x16x32_bf16(af[0][fm], bf0[fn], acc[fm][fn], 0, 0, 0);
                acc[fm][fn] = __builtin_amdgcn_mfma_f32_16x16x32_bf16(af[1][fm], bf1[fn], acc[fm][fn], 0, 0, 0);
            }

        // ---- epilogue ----
        const bool diag = (z < 2) && (c == 0) && (t == 0);   // bj==bi only here
        if (diag) {
            float ts = 0.f;
#pragma unroll
            for (int fm = 0; fm < 4; ++fm)
#pragma unroll
                for (int fn = 0; fn < 4; ++fn)
#pragma unroll
                    for (int rr = 0; rr < 4; ++rr) {
                        float term = __builtin_amdgcn_exp2f(fminf(acc[fm][fn][rr], 0.f));
                        int gm = wm + fm * 16 + lhi * 4 + rr;
                        int gn = wn + fn * 16 + llo;
                        if (gm == gn && a0 + gm < rA) term = 1.0f;
                        ts += term;
                    }
            local += ts;                       // diagonal tile, weight 1
        } else {
            float mx = -3.4e38f;
#pragma unroll
            for (int fm = 0; fm < 4; ++fm)
#pragma unroll
                for (int fn = 0; fn < 4; ++fn) {
                    f32x4 a = acc[fm][fn];
                    mx = fmaxf(mx, fmaxf(fmaxf(a[0], a[1]), fmaxf(a[2], a[3])));
                }
            if (__any(mx > THR)) {
                float ts = 0.f;
#pragma unroll
                for (int fm = 0; fm < 4; ++fm)
#pragma unroll
                    for (int fn = 0; fn < 4; ++fn)
#pragma unroll
                        for (int rr = 0; rr < 4; ++rr)
                            ts += __builtin_amdgcn_exp2f(fminf(acc[fm][fn][rr], 0.f));
                if (z < 2) ts *= 2.f;          // symmetric off-diagonal
                local += ts;
            }
        }

#pragma unroll
        for (int fn = 0; fn < 4; ++fn) vcur[fn] = vnxt[fn];

        asm volatile("s_waitcnt lgkmcnt(0)" ::: "memory");
        __builtin_amdgcn_s_barrier();          // B2: Bbuf[cur] free for overwrite
    }

    // ---- block reduction -> per-block partial ----
#pragma unroll
    for (int m = 32; m > 0; m >>= 1) local += __shfl_xor(local, m, 64);
    if (lane == 0) red[w] = local;
    __syncthreads();
    if (tid == 0) part[lin] = red[0] + red[1] + red[2] + red[3];
}

// ---------------------------------------------------------------------------
// Final reduce over 3 x NT x CH partials (double), combine MMD.
// ---------------------------------------------------------------------------
__global__ void reduce_kernel(const float* __restrict__ part, float* __restrict__ out,
                              int seg, int nX, int nY) {
    __shared__ double sh[3][4];
    const int tid = threadIdx.x;
    double s0 = 0, s1 = 0, s2 = 0;
    for (int i = tid; i < seg; i += 256) {
        s0 += (double)part[i];
        s1 += (double)part[seg + i];
        s2 += (double)part[2 * seg + i];
    }
#pragma unroll
    for (int m = 32; m > 0; m >>= 1) {
        s0 += __shfl_xor(s0, m, 64);
        s1 += __shfl_xor(s1, m, 64);
        s2 += __shfl_xor(s2, m, 64);
    }
    const int w = tid >> 6, lane = tid & 63;
    if (lane == 0) { sh[0][w] = s0; sh[1][w] = s1; sh[2][w] = s2; }
    __syncthreads();
    if (tid == 0) {
        double xx = sh[0][0] + sh[0][1] + sh[0][2] + sh[0][3];
        double yy = sh[1][0] + sh[1][1] + sh[1][2] + sh[1][3];
        double xy = sh[2][0] + sh[2][1] + sh[2][2] + sh[2][3];
        out[0] = (float)(xx / ((double)nX * (double)nX)
                       + yy / ((double)nY * (double)nY)
                       - 2.0 * xy / ((double)nX * (double)nY));
    }
}

extern "C" void kernel_launch(void* const* d_in, const int* in_sizes, int n_in,
                              void* d_out, int out_size, void* d_ws, size_t ws_size,
                              hipStream_t stream) {
    const float* X = (const float*)d_in[0];
    const float* Y = (const float*)d_in[1];
    const int nX = in_sizes[0] / D;
    const int nY = in_sizes[1] / D;
    const int nMax = nX > nY ? nX : nY;
    const int NT   = (nMax + TILE - 1) / TILE;
    const int padN = NT * TILE;
    const int CH   = (NT + W - 1) / W;

    // ws layout (256B-aligned):
    //   part[3*NT*CH] f32 | nx[padN] f32 | ny[padN] f32 | Xbf[padN*64] bf16 | Ybf[padN*64] bf16
    char* ws = (char*)d_ws;
    size_t off = 0;
    float* part = (float*)(ws + off); off += ((size_t)3 * NT * CH * 4 + 255) & ~(size_t)255;
    float* nxp  = (float*)(ws + off); off += ((size_t)padN * 4 + 255) & ~(size_t)255;
    float* nyp  = (float*)(ws + off); off += ((size_t)padN * 4 + 255) & ~(size_t)255;
    unsigned short* Xbf = (unsigned short*)(ws + off); off += ((size_t)padN * D * 2 + 255) & ~(size_t)255;
    unsigned short* Ybf = (unsigned short*)(ws + off);

    int chunks = 2 * padN * 8;
    prep_kernel<<<(chunks + 255) / 256, 256, 0, stream>>>(X, Y, Xbf, Ybf, nxp, nyp, nX, nY, padN);

    dim3 grid(CH, NT, 3);
    gram_kernel<<<grid, 256, 0, stream>>>(Xbf, Ybf, nxp, nyp, nX, nY, NT, CH, part);

    reduce_kernel<<<1, 256, 0, stream>>>(part, (float*)d_out, NT * CH, nX, nY);
}

// Round 5
// 120.747 us; speedup vs baseline: 11.1802x; 1.0653x over previous
//
#include <hip/hip_runtime.h>

#define D 64
#define TILE 128
#define W 16            // B-tiles per block (chunk length)

typedef __attribute__((ext_vector_type(8))) short short8;
typedef __attribute__((ext_vector_type(4))) float f32x4;
typedef __attribute__((ext_vector_type(8))) unsigned short ushort8;

#define CC     (-0.7213475204444817f)   // -log2(e)/(2*sigma^2), sigma=1
#define SCALE  (1.2011224087864498f)    // sqrt(2*log2(e)); dot(scaled) = -2C*dot
#define THR    (-28.0f)                 // drop terms < 2^-28: total mass < 3 -> <3e-8 on output

// ---------------------------------------------------------------------------
// Prep: fp32 -> bf16 (RNE), PRE-SCALED by sqrt(2*log2 e), pre-swizzled within
// each 128B row (chunk' = chunk ^ (row&7), chunk = 8 bf16 = 16B).
// Norms stored PRE-MULTIPLIED by C. Padded rows: zeros + C*1e30.
// ---------------------------------------------------------------------------
__global__ void prep_kernel(const float* __restrict__ X, const float* __restrict__ Y,
                            unsigned short* __restrict__ Xbf, unsigned short* __restrict__ Ybf,
                            float* __restrict__ nx, float* __restrict__ ny,
                            int nX, int nY, int padN) {
    int t = blockIdx.x * blockDim.x + threadIdx.x;
    int half = padN * 8;
    if (t >= 2 * half) return;

    const float* src; unsigned short* dst; float* nrm; int n; int tt;
    if (t < half) { src = X; dst = Xbf; nrm = nx; n = nX; tt = t; }
    else          { src = Y; dst = Ybf; nrm = ny; n = nY; tt = t - half; }

    int row = tt >> 3, c8 = tt & 7;

    float v[8];
    float ss = 0.f;
    if (row < n) {
        const float4* p = (const float4*)(src + (size_t)row * D + c8 * 8);
        float4 f0 = p[0], f1 = p[1];
        v[0] = f0.x; v[1] = f0.y; v[2] = f0.z; v[3] = f0.w;
        v[4] = f1.x; v[5] = f1.y; v[6] = f1.z; v[7] = f1.w;
#pragma unroll
        for (int i = 0; i < 8; ++i) ss += v[i] * v[i];
    } else {
#pragma unroll
        for (int i = 0; i < 8; ++i) v[i] = 0.f;
    }

    ss += __shfl_xor(ss, 1, 64);
    ss += __shfl_xor(ss, 2, 64);
    ss += __shfl_xor(ss, 4, 64);

    ushort8 o;
#pragma unroll
    for (int i = 0; i < 8; ++i) {
        unsigned u = __float_as_uint(v[i] * SCALE);
        o[i] = (unsigned short)((u + 0x7fffu + ((u >> 16) & 1u)) >> 16);   // RNE
    }
    *(ushort8*)(dst + (size_t)row * D + ((c8 ^ (row & 7)) << 3)) = o;

    if (c8 == 0) nrm[row] = (row < n) ? (CC * ss) : (CC * 1e30f);
}

// ---------------------------------------------------------------------------
// Stage one 16KB B-tile (bf16, pre-swizzled rows) to LDS, linear dest.
// ---------------------------------------------------------------------------
__device__ static inline void stage_tile(const char* src, char* dst, int w, int lane) {
#pragma unroll
    for (int cIdx = 0; cIdx < 4; ++cIdx) {
        int off = w * 4096 + cIdx * 1024;
        __builtin_amdgcn_global_load_lds(
            (const __attribute__((address_space(1))) void*)(src + off + lane * 16),
            (__attribute__((address_space(3))) void*)(dst + off), 16, 0, 0);
    }
}

// ---------------------------------------------------------------------------
// Persistent-A gram kernel. A-panel fragments + A-norms (u4, the MFMA C-in)
// live in registers for the whole block. B-tiles + B-norms double-buffered in
// LDS; per-iter exactly 5 gload_lds/wave -> counted vmcnt(5), loads stay in
// flight across both barriers (no in-loop drain). First MFMA per fragment
// takes C-in = u4[fm] (A-norm fold, zero per-tile init cost). Fast path:
// bound = max(acc)+max(v) vs THR, one __any branch -> no exp work.
// z=0: xx (bj>=bi, x2 off-diag), z=1: yy, z=2: xy (full rows).
// ---------------------------------------------------------------------------
__launch_bounds__(256, 3)
__global__ void gram_kernel(const unsigned short* __restrict__ Xbf,
                            const unsigned short* __restrict__ Ybf,
                            const float* __restrict__ nx, const float* __restrict__ ny,
                            int nX, int nY, int NT, int CH, float* __restrict__ part) {
    __shared__ unsigned short Bbuf[2][TILE * D];   // 2 x 16KB
    __shared__ float Bnorm[2][TILE];               // 2 x 512B
    __shared__ float red[4];

    const int c   = blockIdx.x;
    const int bi  = blockIdx.y;
    const int z   = blockIdx.z;
    const int tid = threadIdx.x;
    const int lin = (z * NT + bi) * CH + c;

    const int bj0 = (z < 2 ? bi : 0) + c * W;
    int ntiles = NT - bj0; if (ntiles > W) ntiles = W;
    if (ntiles <= 0) { if (tid == 0) part[lin] = 0.f; return; }

    const unsigned short* Abase; const unsigned short* Bbase;
    const float* nA; const float* nB; int rA;
    if (z == 0)      { Abase = Xbf; Bbase = Xbf; nA = nx; nB = nx; rA = nX; }
    else if (z == 1) { Abase = Ybf; Bbase = Ybf; nA = ny; nB = ny; rA = nY; }
    else             { Abase = Xbf; Bbase = Ybf; nA = nx; nB = ny; rA = nX; }

    const int a0 = bi * TILE;
    const int w = tid >> 6, lane = tid & 63;
    const int wm = (w & 1) * 64, wn = (w >> 1) * 64;
    const int lhi = lane >> 4, llo = lane & 15;
    const int sw = llo & 7;

    // ---------------- prologue ----------------
    const char*  Bsrc = (const char*)(Bbase + (size_t)bj0 * TILE * D);   // +16KB/tile
    const float* nBt  = nB + (size_t)bj0 * TILE;

    stage_tile(Bsrc, (char*)&Bbuf[0][0], w, lane);
    if (lane < 8)
        __builtin_amdgcn_global_load_lds(
            (const __attribute__((address_space(1))) void*)(nBt + w * 32 + lane * 4),
            (__attribute__((address_space(3))) void*)(&Bnorm[0][w * 32]), 16, 0, 0);

    // A fragments straight from global (pre-swizzled, L2-resident)
    const unsigned short* Ab = Abase + (size_t)(a0 + wm) * D;
    short8 af[2][4];
#pragma unroll
    for (int ks = 0; ks < 2; ++ks)
#pragma unroll
        for (int fm = 0; fm < 4; ++fm) {
            int r = fm * 16 + llo;
            af[ks][fm] = *(const short8*)&Ab[r * D + (((ks * 4 + lhi) ^ sw) << 3)];
        }

    // A-norms as f32x4 = exact MFMA C-register layout (row = lhi*4 + reg)
    f32x4 u4[4];
    {
        const float* uptr = nA + a0 + wm + lhi * 4;
#pragma unroll
        for (int fm = 0; fm < 4; ++fm)
            u4[fm] = *(const f32x4*)(uptr + fm * 16);
    }

    const int bb0 = (lhi ^ sw) << 3;          // element offset, ks=0
    const int bb1 = ((4 + lhi) ^ sw) << 3;    // ks=1

    float local = 0.f;

    // ---------------- main loop over B-tiles ----------------
    for (int t = 0; t < ntiles; ++t) {
        const int cur = t & 1;

        if (t + 1 < ntiles) {
            stage_tile(Bsrc + (size_t)(t + 1) * TILE * D * 2, (char*)&Bbuf[cur ^ 1][0], w, lane);
            if (lane < 8)
                __builtin_amdgcn_global_load_lds(
                    (const __attribute__((address_space(1))) void*)(nBt + (size_t)(t + 1) * TILE + w * 32 + lane * 4),
                    (__attribute__((address_space(3))) void*)(&Bnorm[cur ^ 1][w * 32]), 16, 0, 0);
            // exactly the 5 loads just issued stay in flight; stage(t) drained
            asm volatile("s_waitcnt vmcnt(5)" ::: "memory");
        } else {
            asm volatile("s_waitcnt vmcnt(0)" ::: "memory");
        }
        __builtin_amdgcn_s_barrier();          // B1: Bbuf[cur]/Bnorm[cur] ready

        // B fragments + B-norms from LDS (norm reads broadcast: free)
        short8 bf0[4], bf1[4];
        float vc[4];
#pragma unroll
        for (int fn = 0; fn < 4; ++fn) {
            int r = (wn + fn * 16 + llo) * D;
            bf0[fn] = *(const short8*)&Bbuf[cur][r + bb0];
            bf1[fn] = *(const short8*)&Bbuf[cur][r + bb1];
            vc[fn]  = Bnorm[cur][wn + fn * 16 + llo];
        }

        // acc = u4[fm] (C-in) + dot-part; after both k-steps: acc = C*n_i - 2C*dot
        f32x4 acc[4][4];
#pragma unroll
        for (int fm = 0; fm < 4; ++fm)
#pragma unroll
            for (int fn = 0; fn < 4; ++fn) {
                acc[fm][fn] = __builtin_amdgcn_mfma_f32_16x16x32_bf16(af[0][fm], bf0[fn], u4[fm], 0, 0, 0);
                acc[fm][fn] = __builtin_amdgcn_mfma_f32_16x16x32_bf16(af[1][fm], bf1[fn], acc[fm][fn], 0, 0, 0);
            }

        // ---- epilogue ----
        const bool diag = (z < 2) && (c == 0) && (t == 0);   // bj==bi tile
        if (diag) {
            float ts = 0.f;
#pragma unroll
            for (int fm = 0; fm < 4; ++fm)
#pragma unroll
                for (int fn = 0; fn < 4; ++fn)
#pragma unroll
                    for (int rr = 0; rr < 4; ++rr) {
                        float term = __builtin_amdgcn_exp2f(fminf(acc[fm][fn][rr] + vc[fn], 0.f));
                        int gm = wm + fm * 16 + lhi * 4 + rr;
                        int gn = wn + fn * 16 + llo;
                        if (gm == gn && a0 + gm < rA) term = 1.0f;
                        ts += term;
                    }
            local += ts;                       // diagonal tile, weight 1
        } else {
            // upper bound on max(acc + v): max(acc) + max(v); triples -> v_max3
            float m[16];
#pragma unroll
            for (int fm = 0; fm < 4; ++fm)
#pragma unroll
                for (int fn = 0; fn < 4; ++fn) {
                    f32x4 a = acc[fm][fn];
                    m[fm * 4 + fn] = fmaxf(fmaxf(fmaxf(a[0], a[1]), a[2]), a[3]);
                }
            float p0 = fmaxf(fmaxf(m[0],  m[1]),  m[2]);
            float p1 = fmaxf(fmaxf(m[3],  m[4]),  m[5]);
            float p2 = fmaxf(fmaxf(m[6],  m[7]),  m[8]);
            float p3 = fmaxf(fmaxf(m[9],  m[10]), m[11]);
            float p4 = fmaxf(fmaxf(m[12], m[13]), m[14]);
            float mx = fmaxf(fmaxf(fmaxf(p0, p1), fmaxf(p2, p3)), fmaxf(p4, m[15]));
            float vmax = fmaxf(fmaxf(vc[0], vc[1]), fmaxf(vc[2], vc[3]));
            if (__any(mx + vmax > THR)) {
                float ts = 0.f;
#pragma unroll
                for (int fm = 0; fm < 4; ++fm)
#pragma unroll
                    for (int fn = 0; fn < 4; ++fn)
#pragma unroll
                        for (int rr = 0; rr < 4; ++rr)
                            ts += __builtin_amdgcn_exp2f(fminf(acc[fm][fn][rr] + vc[fn], 0.f));
                if (z < 2) ts *= 2.f;          // symmetric off-diagonal
                local += ts;
            }
        }

        asm volatile("s_waitcnt lgkmcnt(0)" ::: "memory");
        __builtin_amdgcn_s_barrier();          // B2: Bbuf[cur] free for overwrite
    }

    // ---- block reduction -> per-block partial ----
#pragma unroll
    for (int m2 = 32; m2 > 0; m2 >>= 1) local += __shfl_xor(local, m2, 64);
    if (lane == 0) red[w] = local;
    __syncthreads();
    if (tid == 0) part[lin] = red[0] + red[1] + red[2] + red[3];
}

// ---------------------------------------------------------------------------
// Final reduce over 3 x NT x CH partials (double), combine MMD.
// ---------------------------------------------------------------------------
__global__ void reduce_kernel(const float* __restrict__ part, float* __restrict__ out,
                              int seg, int nX, int nY) {
    __shared__ double sh[3][4];
    const int tid = threadIdx.x;
    double s0 = 0, s1 = 0, s2 = 0;
    for (int i = tid; i < seg; i += 256) {
        s0 += (double)part[i];
        s1 += (double)part[seg + i];
        s2 += (double)part[2 * seg + i];
    }
#pragma unroll
    for (int m = 32; m > 0; m >>= 1) {
        s0 += __shfl_xor(s0, m, 64);
        s1 += __shfl_xor(s1, m, 64);
        s2 += __shfl_xor(s2, m, 64);
    }
    const int w = tid >> 6, lane = tid & 63;
    if (lane == 0) { sh[0][w] = s0; sh[1][w] = s1; sh[2][w] = s2; }
    __syncthreads();
    if (tid == 0) {
        double xx = sh[0][0] + sh[0][1] + sh[0][2] + sh[0][3];
        double yy = sh[1][0] + sh[1][1] + sh[1][2] + sh[1][3];
        double xy = sh[2][0] + sh[2][1] + sh[2][2] + sh[2][3];
        out[0] = (float)(xx / ((double)nX * (double)nX)
                       + yy / ((double)nY * (double)nY)
                       - 2.0 * xy / ((double)nX * (double)nY));
    }
}

extern "C" void kernel_launch(void* const* d_in, const int* in_sizes, int n_in,
                              void* d_out, int out_size, void* d_ws, size_t ws_size,
                              hipStream_t stream) {
    const float* X = (const float*)d_in[0];
    const float* Y = (const float*)d_in[1];
    const int nX = in_sizes[0] / D;
    const int nY = in_sizes[1] / D;
    const int nMax = nX > nY ? nX : nY;
    const int NT   = (nMax + TILE - 1) / TILE;
    const int padN = NT * TILE;
    const int CH   = (NT + W - 1) / W;

    // ws layout (256B-aligned):
    //   part[3*NT*CH] f32 | nx[padN] f32 | ny[padN] f32 | Xbf[padN*64] bf16 | Ybf[padN*64] bf16
    char* ws = (char*)d_ws;
    size_t off = 0;
    float* part = (float*)(ws + off); off += ((size_t)3 * NT * CH * 4 + 255) & ~(size_t)255;
    float* nxp  = (float*)(ws + off); off += ((size_t)padN * 4 + 255) & ~(size_t)255;
    float* nyp  = (float*)(ws + off); off += ((size_t)padN * 4 + 255) & ~(size_t)255;
    unsigned short* Xbf = (unsigned short*)(ws + off); off += ((size_t)padN * D * 2 + 255) & ~(size_t)255;
    unsigned short* Ybf = (unsigned short*)(ws + off);

    int chunks = 2 * padN * 8;
    prep_kernel<<<(chunks + 255) / 256, 256, 0, stream>>>(X, Y, Xbf, Ybf, nxp, nyp, nX, nY, padN);

    dim3 grid(CH, NT, 3);
    gram_kernel<<<grid, 256, 0, stream>>>(Xbf, Ybf, nxp, nyp, nX, nY, NT, CH, part);

    reduce_kernel<<<1, 256, 0, stream>>>(part, (float*)d_out, NT * CH, nX, nY);
}